// Round 2
// baseline (4426.429 us; speedup 1.0000x reference)
//
#include <hip/hip_runtime.h>
#include <hip/hip_bf16.h>

#define ALPHA 0.01f
#define BETA  0.125f
#define NN    2048
#define NOBS  512
#define NB    16
#define TT    512
#define NBLK  128
#define NTHR  256

typedef __attribute__((ext_vector_type(8))) short short8;
typedef __attribute__((ext_vector_type(4))) float f32x4;

// Persistent device-side buffers (no ws_size assumptions).
__device__ __align__(16) unsigned short g_wbf[NN * NN];        // W bf16, [i][k]
__device__ __align__(16) float          g_xf[2][NB * NN];      // fp32 state
__device__ __align__(16) unsigned short g_xbf[2][NB * NN];     // bf16 state
__device__ __align__(16) float          g_outT[TT][NB][NN];    // output, (t,b,n) layout, 64 MB
__device__ __align__(16) float          g_tchT[TT][NB][NOBS];  // teacher, (t,b,n) layout, 16 MB
__device__ unsigned int g_bar;                                 // grid barrier counter

__device__ inline unsigned short f2bf(float f) {
    unsigned int x = __builtin_bit_cast(unsigned int, f);
    unsigned int r = (x + 0x7fffu + ((x >> 16) & 1u)) >> 16;   // RNE
    return (unsigned short)r;
}

__global__ void convert_w_kernel(const float* __restrict__ w) {
    int n4 = NN * NN / 4;
    const float4* w4 = reinterpret_cast<const float4*>(w);
    for (int i = blockIdx.x * blockDim.x + threadIdx.x; i < n4;
         i += gridDim.x * blockDim.x) {
        float4 v = w4[i];
        ushort4 o;
        o.x = f2bf(v.x); o.y = f2bf(v.y); o.z = f2bf(v.z); o.w = f2bf(v.w);
        reinterpret_cast<ushort4*>(g_wbf)[i] = o;
    }
}

// teach (NB, NOBS, TT) -> g_tchT (TT, NB, NOBS), 32x32 LDS tiles.
__global__ void tch_transpose_kernel(const float* __restrict__ tch) {
    __shared__ float tile[32][33];
    int b  = blockIdx.z;
    int n0 = blockIdx.x * 32;
    int t0 = blockIdx.y * 32;
    int j  = threadIdx.x & 31;
    int i4 = threadIdx.x >> 5;   // 0..7
#pragma unroll
    for (int r = 0; r < 4; ++r) {
        int i = r * 8 + i4;      // n index
        tile[i][j] = tch[((size_t)b * NOBS + (n0 + i)) * TT + (t0 + j)];
    }
    __syncthreads();
#pragma unroll
    for (int r = 0; r < 4; ++r) {
        int i = r * 8 + i4;      // t index
        g_tchT[t0 + i][b][n0 + j] = tile[j][i];
    }
}

// x0 build + state init + out col 0 + barrier reset.
__global__ void init_kernel(const float* __restrict__ xt) {
    int idx = blockIdx.x * blockDim.x + threadIdx.x;  // 16*2048
    if (idx == 0) g_bar = 0u;
    if (idx >= NB * NN) return;
    int b = idx >> 11;
    int i = idx & (NN - 1);
    float v = (i < NOBS) ? xt[(size_t)b * NOBS * TT + (size_t)i * TT + 0] : 0.0f;
    g_outT[0][b][i] = v;
    g_xf[0][idx]  = v;
    g_xbf[0][idx] = f2bf(v);
}

// All 512 steps in one kernel. 128 blocks x 256 threads; block owns 16 neurons.
__global__ __launch_bounds__(NTHR)
void rnn_persistent_kernel() {
    __shared__ __align__(16) unsigned short wlds[16 * NN];  // 64 KB, XOR-swizzled
    __shared__ float red[4][16][16];                        // 4 KB

    int tid = threadIdx.x;
    int blk = blockIdx.x;
    int i0  = blk << 4;   // neuron tile base

    // Load W slice (16 rows) into LDS, swizzled: 16B chunk c of row r -> c ^ (r&7).
    {
        const short8* src = reinterpret_cast<const short8*>(g_wbf + (size_t)i0 * NN);
        short8* dst = reinterpret_cast<short8*>(wlds);
        for (int i = tid; i < 16 * NN / 8; i += NTHR) {
            int row = i >> 8, c = i & 255;
            dst[(row << 8) | (c ^ (row & 7))] = src[i];
        }
    }
    __syncthreads();

    int wv = tid >> 6;    // wave -> K slice of 512
    int l  = tid & 63;
    int ln = l & 15;      // A batch-row / B neuron-row lane
    int kg = l >> 4;      // k-group
    const short8* wldsc = reinterpret_cast<const short8*>(wlds);
    int bbase = ln * 256;
    int bswz  = ln & 7;

    for (int s = 0; s < TT; ++s) {
        int p = s & 1;
        const unsigned short* xbf = g_xbf[p];
        const float*          xf  = g_xf[p];
        const short8* A = reinterpret_cast<const short8*>(xbf + (size_t)ln * NN + wv * 512 + kg * 8);

        f32x4 acc = {0.f, 0.f, 0.f, 0.f};
#pragma unroll
        for (int it = 0; it < 16; ++it) {
            short8 a = A[it * 4];
            short8 b = wldsc[bbase + (((wv * 64) + (it * 4) + kg) ^ bswz)];
            acc = __builtin_amdgcn_mfma_f32_16x16x32_bf16(a, b, acc, 0, 0, 0);
        }

#pragma unroll
        for (int r = 0; r < 4; ++r) red[wv][kg * 4 + r][ln] = acc[r];
        __syncthreads();

        int b = tid >> 4;   // batch
        int n = tid & 15;   // local neuron
        float sum = red[0][b][n] + red[1][b][n] + red[2][b][n] + red[3][b][n];
        int ig = i0 + n;
        size_t sidx = (size_t)b * NN + ig;
        float snew = (1.0f - ALPHA) * xf[sidx] + ALPHA * sum;

        if (s > 0) g_outT[s][b][ig] = snew;

        float nx = snew;
        if (s < TT - 1 && ig < NOBS)
            nx = BETA * g_tchT[s + 1][b][ig] + (1.0f - BETA) * snew;

        g_xf[p ^ 1][sidx]  = nx;
        g_xbf[p ^ 1][sidx] = f2bf(nx);
        __syncthreads();   // all waves' stores drained (vmcnt) before leader releases

        if (tid == 0) {
            __hip_atomic_fetch_add(&g_bar, 1u, __ATOMIC_RELEASE, __HIP_MEMORY_SCOPE_AGENT);
            unsigned int target = (unsigned int)(s + 1) * NBLK;
            while (__hip_atomic_load(&g_bar, __ATOMIC_RELAXED, __HIP_MEMORY_SCOPE_AGENT) < target)
                __builtin_amdgcn_s_sleep(4);
            // acquire: make other blocks' state stores visible (L1/L2 inv)
            (void)__hip_atomic_fetch_add(&g_bar, 0u, __ATOMIC_ACQUIRE, __HIP_MEMORY_SCOPE_AGENT);
        }
        __syncthreads();
    }
}

// out (b,n,t) <- g_outT (t,b,n), 32x32 LDS tiles.
__global__ void out_transpose_kernel(float* __restrict__ out) {
    __shared__ float tile[32][33];
    int b  = blockIdx.z;
    int n0 = blockIdx.x * 32;
    int t0 = blockIdx.y * 32;
    int j  = threadIdx.x & 31;
    int i4 = threadIdx.x >> 5;
#pragma unroll
    for (int r = 0; r < 4; ++r) {
        int i = r * 8 + i4;      // t index
        tile[i][j] = g_outT[t0 + i][b][n0 + j];
    }
    __syncthreads();
#pragma unroll
    for (int r = 0; r < 4; ++r) {
        int i = r * 8 + i4;      // n index
        out[((size_t)b * NN + (n0 + i)) * TT + (t0 + j)] = tile[j][i];
    }
}

extern "C" void kernel_launch(void* const* d_in, const int* in_sizes, int n_in,
                              void* d_out, int out_size, void* d_ws, size_t ws_size,
                              hipStream_t stream) {
    const float* xt = (const float*)d_in[0];   // (16, 512, 512)
    const float* w  = (const float*)d_in[1];   // (2048, 2048)
    float* out = (float*)d_out;                // (16, 2048, 512)

    hipLaunchKernelGGL(convert_w_kernel, dim3(1024), dim3(256), 0, stream, w);
    hipLaunchKernelGGL(tch_transpose_kernel, dim3(NOBS / 32, TT / 32, NB), dim3(256), 0, stream, xt);
    hipLaunchKernelGGL(init_kernel, dim3(128), dim3(256), 0, stream, xt);
    hipLaunchKernelGGL(rnn_persistent_kernel, dim3(NBLK), dim3(NTHR), 0, stream);
    hipLaunchKernelGGL(out_transpose_kernel, dim3(NN / 32, TT / 32, NB), dim3(256), 0, stream, out);
}

// Round 3
// 2022.017 us; speedup vs baseline: 2.1891x; 2.1891x over previous
//
#include <hip/hip_runtime.h>
#include <hip/hip_bf16.h>

#define ALPHA 0.01f
#define BETA  0.125f
#define NN    2048
#define NOBS  512
#define NB    16
#define TT    512
#define NBLK  128
#define NTHR  256
#define NGRP  256   // 2 recurrence steps per group

typedef __attribute__((ext_vector_type(8))) short short8;
typedef __attribute__((ext_vector_type(4))) float f32x4;
typedef __attribute__((ext_vector_type(2))) unsigned long long ull2;

// ---- persistent device buffers ----
__device__ __align__(16) unsigned short g_X[NN * NN];     // X = E^T: X[c][k] = alpha*c_c*W[c][k]
__device__ __align__(16) unsigned short g_XT[NN * NN];    // XT[k][c] = X[c][k]
__device__ __align__(16) unsigned short g_E2T[NN * NN];   // E2T[c][k] = E2[k][c]
__device__ __align__(16) unsigned short g_zbf[2][NB * NN];// bf16 state (device-coherent access)
__device__ __align__(16) float          g_tchT[TT][NB][NOBS];   // beta*teacher, (t,b,n)
__device__ __align__(16) unsigned short g_tchTb[TT][NB][NOBS];  // bf16 of same
__device__ __align__(16) float          g_outT[TT][NB][NN];     // outputs, (t,b,n)
__device__ unsigned int g_bar;

__device__ inline unsigned short f2bf(float f) {
    unsigned int x = __builtin_bit_cast(unsigned int, f);
    unsigned int r = (x + 0x7fffu + ((x >> 16) & 1u)) >> 16;   // RNE
    return (unsigned short)r;
}
__device__ inline float bf2f(unsigned short u) {
    unsigned int x = ((unsigned int)u) << 16;
    return __builtin_bit_cast(float, x);
}
__device__ inline float dcoef(int i) {            // diag of A (exact)
    return (i < NOBS) ? (0.99f * 0.875f) : 0.99f;
}

// ---- setup: X[c][k] = alpha * c_c * W[c][k] (bf16) ----
__global__ void build_x_kernel(const float* __restrict__ w) {
    int n4 = NN * NN / 4;
    const float4* w4 = reinterpret_cast<const float4*>(w);
    for (int i = blockIdx.x * blockDim.x + threadIdx.x; i < n4;
         i += gridDim.x * blockDim.x) {
        int row = (i * 4) >> 11;
        float sc = ALPHA * ((row < NOBS) ? 0.875f : 1.0f);
        float4 v = w4[i];
        ushort4 o;
        o.x = f2bf(v.x * sc); o.y = f2bf(v.y * sc); o.z = f2bf(v.z * sc); o.w = f2bf(v.w * sc);
        reinterpret_cast<ushort4*>(g_X)[i] = o;
    }
}

// ---- setup: XT[k][c] = X[c][k], 32x32 tiles ----
__global__ void build_xt_kernel(const float* __restrict__ w) {
    __shared__ float tile[32][33];
    int r0 = blockIdx.x * 32;   // W row   (= X row c)
    int k0 = blockIdx.y * 32;   // W col   (= k)
    int j  = threadIdx.x & 31;
    int i4 = threadIdx.x >> 5;
#pragma unroll
    for (int r = 0; r < 4; ++r) {
        int i = r * 8 + i4;
        tile[i][j] = w[(size_t)(r0 + i) * NN + (k0 + j)];
    }
    __syncthreads();
#pragma unroll
    for (int r = 0; r < 4; ++r) {
        int i = r * 8 + i4;     // k-local
        int c = r0 + j;
        float sc = ALPHA * ((c < NOBS) ? 0.875f : 1.0f);
        g_XT[(size_t)(k0 + i) * NN + c] = f2bf(tile[j][i] * sc);
    }
}

// ---- setup GEMM: E2T = (d_m + d_n)*X + X@X   (C[m][n] = sum_k X[m][k]*XT[n][k]) ----
__global__ __launch_bounds__(256)
void gemm_e2_kernel() {
    int tid = threadIdx.x;
    int wv  = tid >> 6;
    int l   = tid & 63;
    int ln  = l & 15;
    int kg  = l >> 4;
    int m0  = blockIdx.x * 64 + wv * 16;
    int n0  = blockIdx.y * 64;

    f32x4 acc[4] = {{0,0,0,0},{0,0,0,0},{0,0,0,0},{0,0,0,0}};
    for (int kk = 0; kk < NN; kk += 32) {
        short8 a = *reinterpret_cast<const short8*>(g_X + (size_t)(m0 + ln) * NN + kk + kg * 8);
#pragma unroll
        for (int cq = 0; cq < 4; ++cq) {
            short8 b = *reinterpret_cast<const short8*>(g_XT + (size_t)(n0 + cq * 16 + ln) * NN + kk + kg * 8);
            acc[cq] = __builtin_amdgcn_mfma_f32_16x16x32_bf16(a, b, acc[cq], 0, 0, 0);
        }
    }
#pragma unroll
    for (int cq = 0; cq < 4; ++cq) {
#pragma unroll
        for (int r = 0; r < 4; ++r) {
            int m = m0 + kg * 4 + r;          // D row = (l>>4)*4 + r
            int n = n0 + cq * 16 + ln;        // D col = l&15
            float xv = bf2f(g_X[(size_t)m * NN + n]);
            g_E2T[(size_t)m * NN + n] = f2bf((dcoef(m) + dcoef(n)) * xv + acc[cq][r]);
        }
    }
}

// ---- setup: teacher -> (t,b,n), beta-scaled, fp32 + bf16 ----
__global__ void tch_transpose_kernel(const float* __restrict__ tch) {
    __shared__ float tile[32][33];
    int b  = blockIdx.z;
    int n0 = blockIdx.x * 32;
    int t0 = blockIdx.y * 32;
    int j  = threadIdx.x & 31;
    int i4 = threadIdx.x >> 5;
#pragma unroll
    for (int r = 0; r < 4; ++r) {
        int i = r * 8 + i4;
        tile[i][j] = tch[((size_t)b * NOBS + (n0 + i)) * TT + (t0 + j)];
    }
    __syncthreads();
#pragma unroll
    for (int r = 0; r < 4; ++r) {
        int i = r * 8 + i4;      // t-local
        float v = BETA * tile[j][i];
        g_tchT[t0 + i][b][n0 + j]  = v;
        g_tchTb[t0 + i][b][n0 + j] = f2bf(v);
    }
}

// ---- setup: state_0, out col 0, barrier reset ----
__global__ void init_kernel(const float* __restrict__ xt) {
    int idx = blockIdx.x * blockDim.x + threadIdx.x;
    if (idx == 0) g_bar = 0u;
    if (idx >= NB * NN) return;
    int b = idx >> 11;
    int i = idx & (NN - 1);
    float v = (i < NOBS) ? xt[((size_t)b * NOBS + i) * TT + 0] : 0.0f;
    g_outT[0][b][i] = v;
    g_zbf[0][idx] = f2bf(v);
}

// ---- main persistent kernel: 256 groups x 2 steps ----
__global__ __launch_bounds__(NTHR)
void rnn2_kernel(const float* __restrict__ xt) {
    __shared__ __align__(16) unsigned short ET[16 * NN];    // 64 KB, swizzled
    __shared__ __align__(16) unsigned short E2[16 * NN];    // 64 KB, swizzled
    __shared__ float red[3][4][16][16];                     // 12 KB

    int tid = threadIdx.x;
    int i0  = blockIdx.x << 4;

    // load E / E2 column-slices (rows i0..i0+15 of X / E2T) into LDS, swizzled
    {
        const short8* sx = reinterpret_cast<const short8*>(g_X   + (size_t)i0 * NN);
        const short8* s2 = reinterpret_cast<const short8*>(g_E2T + (size_t)i0 * NN);
        short8* dx = reinterpret_cast<short8*>(ET);
        short8* d2 = reinterpret_cast<short8*>(E2);
        for (int i = tid; i < 16 * NN / 8; i += NTHR) {
            int row = i >> 8, c = i & 255;
            int sw = (row << 8) | (c ^ (row & 7));
            dx[sw] = sx[i];
            d2[sw] = s2[i];
        }
    }

    int wv = tid >> 6;
    int l  = tid & 63;
    int ln = l & 15;
    int kg = l >> 4;
    int swz = ln & 7;
    const short8* ETc = reinterpret_cast<const short8*>(ET);
    const short8* E2c = reinterpret_cast<const short8*>(E2);
    int bbase = ln * 256;

    // scalar-part thread mapping + register fp32 state (own 16x16 tile)
    int bb  = tid >> 4;
    int nn  = tid & 15;
    int col = i0 + nn;
    float dn   = dcoef(col);
    float invc = (col < NOBS) ? (1.0f / 0.875f) : 1.0f;
    float sf = (col < NOBS) ? xt[((size_t)bb * NOBS + col) * TT + 0] : 0.0f;

    __syncthreads();

    for (int g = 0; g < NGRP; ++g) {
        int p  = g & 1;
        int t1 = 2 * g + 1;
        int t2 = 2 * g + 2;

        // z (state) fragments via device-coherent 8B atomic loads
        const unsigned long long* zp = reinterpret_cast<const unsigned long long*>(
            g_zbf[p] + (size_t)ln * NN + wv * 512 + kg * 8);

        f32x4 a1 = {0,0,0,0}, a2 = {0,0,0,0}, a3 = {0,0,0,0};
#pragma unroll
        for (int it = 0; it < 16; ++it) {
            unsigned long long lo = __hip_atomic_load(zp + it * 8,     __ATOMIC_RELAXED, __HIP_MEMORY_SCOPE_AGENT);
            unsigned long long hi = __hip_atomic_load(zp + it * 8 + 1, __ATOMIC_RELAXED, __HIP_MEMORY_SCOPE_AGENT);
            short8 a = __builtin_bit_cast(short8, (ull2){lo, hi});
            int ch = (wv * 64 + it * 4 + kg) ^ swz;
            a1 = __builtin_amdgcn_mfma_f32_16x16x32_bf16(a, ETc[bbase + ch], a1, 0, 0, 0);
            a2 = __builtin_amdgcn_mfma_f32_16x16x32_bf16(a, E2c[bbase + ch], a2, 0, 0, 0);
        }
        // v_{t1} * E  (K = 512)
#pragma unroll
        for (int it = 0; it < 4; ++it) {
            short8 tv = *reinterpret_cast<const short8*>(&g_tchTb[t1][ln][wv * 128 + it * 32 + kg * 8]);
            int ch = (wv * 16 + it * 4 + kg) ^ swz;
            a3 = __builtin_amdgcn_mfma_f32_16x16x32_bf16(tv, ETc[bbase + ch], a3, 0, 0, 0);
        }

#pragma unroll
        for (int r = 0; r < 4; ++r) {
            red[0][wv][kg * 4 + r][ln] = a1[r];
            red[1][wv][kg * 4 + r][ln] = a2[r];
            red[2][wv][kg * 4 + r][ln] = a3[r];
        }
        __syncthreads();

        float r1 = red[0][0][bb][nn] + red[0][1][bb][nn] + red[0][2][bb][nn] + red[0][3][bb][nn];
        float r2 = red[1][0][bb][nn] + red[1][1][bb][nn] + red[1][2][bb][nn] + red[1][3][bb][nn];
        float r3 = red[2][0][bb][nn] + red[2][1][bb][nn] + red[2][2][bb][nn] + red[2][3][bb][nn];

        float vt1 = (col < NOBS) ? g_tchT[t1][bb][col] : 0.0f;
        float vt2 = (col < NOBS && t2 < TT) ? g_tchT[t2][bb][col] : 0.0f;

        // state_{2g+1} core (without vt1) and state_{2g+2}
        float core1 = r1 + dn * sf;
        float s2f   = r2 + dn * dn * sf + r3 + dn * vt1 + vt2;

        if (g > 0) g_outT[2 * g][bb][col] = core1 * invc;        // out col 2g
        g_outT[t1 + 0][bb][col] = (s2f - vt2) * invc;            // out col 2g+1

        sf = s2f;
        __hip_atomic_store(&g_zbf[p ^ 1][(size_t)bb * NN + col], f2bf(s2f),
                           __ATOMIC_RELAXED, __HIP_MEMORY_SCOPE_AGENT);

        __syncthreads();   // all loads + stores of this block complete (vmcnt 0)
        if (tid == 0) {
            __hip_atomic_fetch_add(&g_bar, 1u, __ATOMIC_RELAXED, __HIP_MEMORY_SCOPE_AGENT);
            unsigned int target = (unsigned int)(g + 1) * NBLK;
            while (__hip_atomic_load(&g_bar, __ATOMIC_RELAXED, __HIP_MEMORY_SCOPE_AGENT) < target)
                __builtin_amdgcn_s_sleep(1);
            asm volatile("" ::: "memory");
        }
        __syncthreads();
    }
}

// ---- out (b,n,t) <- g_outT (t,b,n) ----
__global__ void out_transpose_kernel(float* __restrict__ out) {
    __shared__ float tile[32][33];
    int b  = blockIdx.z;
    int n0 = blockIdx.x * 32;
    int t0 = blockIdx.y * 32;
    int j  = threadIdx.x & 31;
    int i4 = threadIdx.x >> 5;
#pragma unroll
    for (int r = 0; r < 4; ++r) {
        int i = r * 8 + i4;      // t
        tile[i][j] = g_outT[t0 + i][b][n0 + j];
    }
    __syncthreads();
#pragma unroll
    for (int r = 0; r < 4; ++r) {
        int i = r * 8 + i4;      // n
        out[((size_t)b * NN + (n0 + i)) * TT + (t0 + j)] = tile[j][i];
    }
}

extern "C" void kernel_launch(void* const* d_in, const int* in_sizes, int n_in,
                              void* d_out, int out_size, void* d_ws, size_t ws_size,
                              hipStream_t stream) {
    const float* xt = (const float*)d_in[0];   // (16, 512, 512)
    const float* w  = (const float*)d_in[1];   // (2048, 2048)
    float* out = (float*)d_out;                // (16, 2048, 512)

    hipLaunchKernelGGL(build_x_kernel, dim3(1024), dim3(256), 0, stream, w);
    hipLaunchKernelGGL(build_xt_kernel, dim3(NN / 32, NN / 32), dim3(256), 0, stream, w);
    hipLaunchKernelGGL(gemm_e2_kernel, dim3(NN / 64, NN / 64), dim3(256), 0, stream);
    hipLaunchKernelGGL(tch_transpose_kernel, dim3(NOBS / 32, TT / 32, NB), dim3(256), 0, stream, xt);
    hipLaunchKernelGGL(init_kernel, dim3(128), dim3(256), 0, stream, xt);
    hipLaunchKernelGGL(rnn2_kernel, dim3(NBLK), dim3(NTHR), 0, stream, xt);
    hipLaunchKernelGGL(out_transpose_kernel, dim3(NN / 32, TT / 32, NB), dim3(256), 0, stream, out);
}